// Round 12
// baseline (275.238 us; speedup 1.0000x reference)
//
#include <hip/hip_runtime.h>
#include <math.h>

typedef unsigned short ushort_t;

#define N_ROWS 32768
#define DIM 256
#define KCENT 2048

// ---------------- fp32 fallback path constants (round-1 kernel) -------------
#define NSPLIT 4
#define CPG (KCENT / NSPLIT)
#define BM 64
#define BN 64
#define BKK 32
#define LSTR 36

#define WS_SUMSQ  0
#define WS_CSQ    32768
#define WS_COUNTS 34816
#define WS_IDX    36864
#define WS_PVAL   69632
#define WS_PIDX   200704

// ---------------- output layout (float offsets) -----------------------------
#define OUT_Q    0
#define OUT_LOSS 8388608
#define OUT_IDX  16777216
#define OUT_CB   16809984
#define OUT_CNT  17334272

// ---------------- MFMA path workspace (byte offsets) ------------------------
// hi-only f16 operands (K=256). 8 partial groups per row (4 g x 2 wn-halves).
#define WB_A2     0UL            // 32768 x 256 f16 = x_hi   (16 MB)
#define WB_B2     16777216UL     // 2048 x 256 f16 = c_hi    (1 MB)
#define WB_PV1    17825792UL     // 8 x 32768 f32  (1 MB)
#define WB_PI1    18874368UL     // 8 x 32768 i32  (1 MB)
#define WB_PV2    19922944UL     // 8 x 32768 f32  (1 MB)
#define WB_SUMSQ  20971520UL     // 32768 f32 (exact ||x||^2)
#define WB_XLO    21102592UL     // 32768 f32 (||x_lo||)
#define WB_XR     21233664UL     // 32768 f32 (||r_x||)
#define WB_CSQ    21364736UL     // 2048 f32 (exact ||c||^2)
#define WB_COUNTS 21372928UL     // 2048 f32
#define WB_IDXBUF 21381120UL     // 32768 i32
#define WB_RLIST  21512192UL     // 32768 i32
#define WB_MISC   21643264UL     // rcnt(i32) @ +0, spare @ +4
#define WB_CT     21643328UL     // 256 x 2048 f32 transposed codebook (2 MB)
#define WB_PBMAX  23740480UL     // 512 x 3 f32 per-block partial maxes
#define WB_TILEC  23746624UL     // 256 i32 per-row-tile done counters
#define WS_NEED   23747648UL

// ---------------- types & helpers -------------------------------------------
typedef _Float16 half4 __attribute__((ext_vector_type(4)));
typedef _Float16 half8 __attribute__((ext_vector_type(8)));
typedef float f32x4 __attribute__((ext_vector_type(4)));

#define ASYNC_COPY16(gptr, lptr)                                               \
  __builtin_amdgcn_global_load_lds(                                            \
      (const __attribute__((address_space(1))) void*)(gptr),                   \
      (__attribute__((address_space(3))) void*)(lptr), 16, 0, 0)

// ============================================================================
//                               MFMA PATH (f16 hi-only + certified window)
// ============================================================================

// fused front-end, 8736 blocks (ONE launch):
//  bid <  8192      : X rows -> f16 hi + norms
//  8192 <= bid<8704 : C cents -> f16 hi + csq + per-block partial maxes
//  8704 <= bid<8736 : transpose C tile -> CT; bid==8704 zeroes counts/rcnt/tilecnt
// (all three ranges independent: read only kernel inputs X/C)
__global__ __launch_bounds__(256) void vq_conv(
    const float* __restrict__ X, const float* __restrict__ C,
    _Float16* __restrict__ A2, _Float16* __restrict__ B2,
    float* __restrict__ sumsq, float* __restrict__ xlo_n, float* __restrict__ xr_n,
    float* __restrict__ csq, float* __restrict__ pbmax,
    float* __restrict__ CT, float* __restrict__ counts, int* __restrict__ rcnt,
    int* __restrict__ tilecnt)
{
  __shared__ float sm[4][3];
  __shared__ float t[64][65];
  const int bid = blockIdx.x;
  const int tid = threadIdx.x;
  const int wave = tid >> 6;
  const int lane = tid & 63;

  if (bid < 8192) {
    int row = bid * 4 + wave;
    float4 v = *(const float4*)(X + (size_t)row * DIM + lane * 4);
    float xv[4] = {v.x, v.y, v.z, v.w};
    half4 hv;
    float s2 = 0.f, l2 = 0.f, r2 = 0.f;
#pragma unroll
    for (int e = 0; e < 4; ++e) {
      float x = xv[e];
      _Float16 h = (_Float16)x;          // RNE
      float hf = (float)h;
      float lrem = x - hf;
      _Float16 l = (_Float16)lrem;
      float lf = (float)l;
      float r = lrem - lf;
      hv[e] = h;
      s2 += x * x; l2 += lf * lf; r2 += r * r;
    }
    *(half4*)(A2 + (size_t)row * 256 + lane * 4) = hv;
#pragma unroll
    for (int off = 32; off > 0; off >>= 1) {
      s2 += __shfl_down(s2, off);
      l2 += __shfl_down(l2, off);
      r2 += __shfl_down(r2, off);
    }
    if (lane == 0) { sumsq[row] = s2; xlo_n[row] = sqrtf(l2); xr_n[row] = sqrtf(r2); }
  } else if (bid < 8704) {
    int cb = bid - 8192;
    int c = cb * 4 + wave;
    float4 v = *(const float4*)(C + (size_t)c * DIM + lane * 4);
    float xv[4] = {v.x, v.y, v.z, v.w};
    half4 hv;
    float s2 = 0.f, l2 = 0.f, r2 = 0.f;
#pragma unroll
    for (int e = 0; e < 4; ++e) {
      float x = xv[e];
      _Float16 h = (_Float16)x;
      float hf = (float)h;
      float lrem = x - hf;
      _Float16 l = (_Float16)lrem;
      float lf = (float)l;
      float r = lrem - lf;
      hv[e] = h;
      s2 += x * x; l2 += lf * lf; r2 += r * r;
    }
    *(half4*)(B2 + (size_t)c * 256 + lane * 4) = hv;
#pragma unroll
    for (int off = 32; off > 0; off >>= 1) {
      s2 += __shfl_down(s2, off);
      l2 += __shfl_down(l2, off);
      r2 += __shfl_down(r2, off);
    }
    if (lane == 0) {
      csq[c] = s2;
      sm[wave][0] = sqrtf(l2);   // ||c_lo||
      sm[wave][1] = sqrtf(s2);   // ||c||
      sm[wave][2] = sqrtf(r2);   // ||r_c||
    }
    __syncthreads();
    if (tid == 0) {
      float m0 = sm[0][0], m1 = sm[0][1], m2 = sm[0][2];
#pragma unroll
      for (int w = 1; w < 4; ++w) {
        m0 = fmaxf(m0, sm[w][0]);
        m1 = fmaxf(m1, sm[w][1]);
        m2 = fmaxf(m2, sm[w][2]);
      }
      pbmax[cb * 3 + 0] = m0;
      pbmax[cb * 3 + 1] = m1;
      pbmax[cb * 3 + 2] = m2;
    }
  } else {
    // transpose tile: cents [c0, c0+64)
    const int c0 = (bid - 8704) * 64;
    if (bid == 8704) {
      for (int i = tid; i < KCENT; i += 256) counts[i] = 0.0f;
      tilecnt[tid] = 0;
      if (tid == 0) { rcnt[0] = 0; rcnt[1] = 0; }
    }
    for (int dt = 0; dt < 4; ++dt) {
      const int d0 = dt * 64;
      __syncthreads();                 // protect prior-iter LDS reads
#pragma unroll
      for (int p = 0; p < 4; ++p) {
        int id = tid + p * 256;        // 0..1023
        int r = id >> 4;               // cent-in-tile 0..63
        int c4 = (id & 15) * 4;        // dim-in-tile 0..60
        float4 v = *(const float4*)(C + (size_t)(c0 + r) * DIM + d0 + c4);
        t[r][c4 + 0] = v.x; t[r][c4 + 1] = v.y;
        t[r][c4 + 2] = v.z; t[r][c4 + 3] = v.w;
      }
      __syncthreads();
#pragma unroll
      for (int p = 0; p < 4; ++p) {
        int id = tid + p * 256;
        int d = id >> 4;               // dim-in-tile
        int cg = (id & 15) * 4;        // cent-in-tile group
        float4 w;
        w.x = t[cg + 0][d]; w.y = t[cg + 1][d];
        w.z = t[cg + 2][d]; w.w = t[cg + 3][d];
        *(float4*)(CT + (size_t)(d0 + d) * KCENT + c0 + cg) = w;
      }
    }
  }
}

// MFMA GEMM (hi*hi only, K=256) + fused argmin(+2nd-min) + LAST-BLOCK tail.
// GEMM core is the round-11 verified structure (56 us, VGPR 120): BK=64,
// 32 barriers, acc[4][4], conflict-free both-sides XOR swizzle, XCD remap.
// Epilogue MUST stay fminf/fmaxf form (med3 variant: VGPR 116->148, r7).
// NEW: per row-tile yb, the 4 contributing g-blocks count via tilecnt[yb]
// (store pv* -> threadfence(release) -> atomicAdd). The 4th block fences
// (acquire) and runs, inline for its 128 rows: maxes + 3-way certify
// (token-identical to old vq_flagreduce) and the exact 8-candidate re-solve
// (token-identical to old vq_rescue8). Full-rescue rows go to rlist for the
// small tier-3 kernel. Removes 1 launch; tail overlaps running blocks.
#define GBM 128
#define GBN 128
#define GBK 64
__global__ __launch_bounds__(256) void vq_mfma(
    const _Float16* __restrict__ A2, const _Float16* __restrict__ B2,
    const float* __restrict__ csq,
    float* pv1, int* pi1, float* pv2,
    const float* __restrict__ X, const float* __restrict__ C,
    const float* __restrict__ sumsq, const float* __restrict__ xlo_n,
    const float* __restrict__ xr_n, const float* __restrict__ pbmax,
    float* __restrict__ out_idx, int* __restrict__ idxbuf,
    float* __restrict__ counts, int* __restrict__ rcnt,
    int* __restrict__ rlist, int* __restrict__ tilecnt)
{
  __shared__ __align__(16) _Float16 sA[GBM * GBK];   // 16 KB
  __shared__ __align__(16) _Float16 sB[GBN * GBK];   // 16 KB
  __shared__ int swin;
  __shared__ float smx[4][3];
  __shared__ float bmx[3];
  __shared__ int l8[128];
  __shared__ int n8;

  const int tid = threadIdx.x;
  const int wave = tid >> 6, lane = tid & 63;
  const int lc = lane & 15, quad = lane >> 4;
  const int wm = wave >> 1, wn = wave & 1;

  // bijective XCD-aware remap: lin = g + 4*y; xcd gets 32 consecutive y x 4 g
  const int lin = blockIdx.x + 4 * blockIdx.y;
  const int xcd = lin & 7;
  const int per = lin >> 3;            // 0..127
  const int yb = xcd * 32 + (per & 31);
  const int g = per >> 5;              // 0..3
  const int row0 = yb * GBM;

  const int rsw = lc & 7;                                   // read-side row swizzle key
  const int sko = (((lane & 7) ^ ((lane >> 3) & 7)) << 3);  // source-side (elems)

  float m1[4][4], m2[4][4];
  int i1v[4][4];
#pragma unroll
  for (int i = 0; i < 4; ++i)
#pragma unroll
    for (int r = 0; r < 4; ++r) { m1[i][r] = 3.4e38f; m2[i][r] = 3.4e38f; i1v[i][r] = 0; }

  const int st_row = lane >> 3;        // 8 rows per wave-call
  const _Float16* gA = A2 + (size_t)(row0 + wave * 32 + st_row) * 256 + sko;

  for (int ct = 0; ct < 4; ++ct) {
    const int cb0 = g * 512 + ct * 128;
    const _Float16* gB = B2 + (size_t)(cb0 + wave * 32 + st_row) * 256 + sko;
    float cs[4];
#pragma unroll
    for (int j = 0; j < 4; ++j) cs[j] = csq[cb0 + wn * 64 + j * 16 + lc];

    f32x4 acc[4][4] = {};

    for (int kt = 0; kt < 4; ++kt) {
      const int k0 = kt * 64;
      __syncthreads();
#pragma unroll
      for (int j = 0; j < 4; ++j) {
        ASYNC_COPY16(gA + (size_t)(j * 8) * 256 + k0, &sA[(wave * 32 + j * 8) * GBK]);
        ASYNC_COPY16(gB + (size_t)(j * 8) * 256 + k0, &sB[(wave * 32 + j * 8) * GBK]);
      }
      __syncthreads();
#pragma unroll
      for (int h = 0; h < 2; ++h) {
        half8 fa[4], fb[4];
#pragma unroll
        for (int i = 0; i < 4; ++i)
          fa[i] = *(const half8*)&sA[(wm * 64 + i * 16 + lc) * GBK
                                     + (((h << 2) + quad) ^ rsw) * 8];
#pragma unroll
        for (int j = 0; j < 4; ++j)
          fb[j] = *(const half8*)&sB[(wn * 64 + j * 16 + lc) * GBK
                                     + (((h << 2) + quad) ^ rsw) * 8];
#pragma unroll
        for (int i = 0; i < 4; ++i)
#pragma unroll
          for (int j = 0; j < 4; ++j)
            acc[i][j] = __builtin_amdgcn_mfma_f32_16x16x32_f16(fa[i], fb[j], acc[i][j], 0, 0, 0);
      }
    }

#pragma unroll
    for (int i = 0; i < 4; ++i) {
#pragma unroll
      for (int j = 0; j < 4; ++j) {
        const int cent = cb0 + wn * 64 + j * 16 + lc;
#pragma unroll
        for (int r = 0; r < 4; ++r) {
          float d = fmaf(-2.0f, acc[i][j][r], cs[j]);
          bool cnd = d < m1[i][r];
          i1v[i][r] = cnd ? cent : i1v[i][r];
          m2[i][r] = fminf(m2[i][r], fmaxf(d, m1[i][r]));
          m1[i][r] = fminf(d, m1[i][r]);
        }
      }
    }
  }

#pragma unroll
  for (int i = 0; i < 4; ++i) {
#pragma unroll
    for (int r = 0; r < 4; ++r) {
      float a1 = m1[i][r], a2 = m2[i][r];
      int ai = i1v[i][r];
#pragma unroll
      for (int off = 1; off < 16; off <<= 1) {
        float o1 = __shfl_xor(a1, off);
        int oi = __shfl_xor(ai, off);
        float o2 = __shfl_xor(a2, off);
        float big = fmaxf(a1, o1);
        bool cnd = o1 < a1;
        a1 = fminf(a1, o1);
        ai = cnd ? oi : ai;
        a2 = fminf(fminf(a2, o2), big);
      }
      if (lc == 0) {
        const int row = row0 + wm * 64 + i * 16 + quad * 4 + r;
        const int slot = g * 2 + wn;
        pv1[slot * N_ROWS + row] = a1;
        pi1[slot * N_ROWS + row] = ai;
        pv2[slot * N_ROWS + row] = a2;
      }
    }
  }

  // ---------------- last-block tail: flagreduce + 8-cand re-solve ------------
  __syncthreads();                     // all waves' pv stores issued
  if (tid == 0) {
    __threadfence();                   // release our pv stores
    int done = atomicAdd(&tilecnt[yb], 1);
    swin = (done == 3) ? 1 : 0;
    n8 = 0;
  }
  __syncthreads();
  if (swin == 0) return;
  __threadfence();                     // acquire siblings' pv stores

  // maxes from pbmax (identical fmax tree to old vq_flagreduce)
  {
    float a0 = 0.f, b1 = 0.f, c2 = 0.f;
    for (int i = tid; i < KCENT / 4; i += 256) {
      a0 = fmaxf(a0, pbmax[i * 3 + 0]);
      b1 = fmaxf(b1, pbmax[i * 3 + 1]);
      c2 = fmaxf(c2, pbmax[i * 3 + 2]);
    }
#pragma unroll
    for (int off = 32; off > 0; off >>= 1) {
      a0 = fmaxf(a0, __shfl_down(a0, off));
      b1 = fmaxf(b1, __shfl_down(b1, off));
      c2 = fmaxf(c2, __shfl_down(c2, off));
    }
    if (lane == 0) { smx[wave][0] = a0; smx[wave][1] = b1; smx[wave][2] = c2; }
    __syncthreads();
    if (tid == 0) {
#pragma unroll
      for (int w = 1; w < 4; ++w) {
        a0 = fmaxf(a0, smx[w][0]);
        b1 = fmaxf(b1, smx[w][1]);
        c2 = fmaxf(c2, smx[w][2]);
      }
      bmx[0] = a0; bmx[1] = b1; bmx[2] = c2;
    }
    __syncthreads();
  }
  const float maxL = bmx[0];   // max ||c_lo||
  const float maxC = bmx[1];   // max ||c||
  const float maxR = bmx[2];   // max ||r_c||

  // classify 128 rows (thread t -> row row0+t); token-identical arithmetic
  if (tid < 128) {
    int r = row0 + tid;
    float fm1 = pv1[r]; int fi1 = pi1[r]; float fm2 = pv2[r];
    float fq = pv2[r];
#pragma unroll
    for (int gg = 1; gg < 8; ++gg) {
      float o1 = pv1[gg * N_ROWS + r];
      int oi = pi1[gg * N_ROWS + r];
      float o2 = pv2[gg * N_ROWS + r];
      fq = fminf(fq, o2);
      float big = fmaxf(fm1, o1);
      bool cnd = o1 < fm1;
      fm1 = fminf(fm1, o1);
      fi1 = cnd ? oi : fi1;
      fm2 = fminf(fminf(fm2, o2), big);
    }
    float xl = xlo_n[r];
    float xr2 = xr_n[r];
    float xn = sqrtf(sumsq[r]);
    float errdot = (xl + xr2) * maxC + (xn + xl + xr2) * (maxL + maxR);
    float W = 2.0f * errdot + 1e-3f;        // certified bound + fp32 slack
    out_idx[r] = (float)fi1;
    idxbuf[r] = fi1;
    if (fm2 - fm1 >= W) {
      atomicAdd(&counts[fi1], 1.0f);
    } else if (fq - fm1 >= W) {
      int p = atomicAdd(&n8, 1);
      l8[p] = r;
    } else {
      int p = atomicAdd(rcnt, 1);
      rlist[p] = r;
    }
  }
  __syncthreads();

  // exact 8-candidate re-solve, wave per row (token-identical to vq_rescue8)
  {
    const int cnt8 = n8;
    const int cslot = lane & 7;
    const int part = lane >> 3;
    for (int ri = wave; ri < cnt8; ri += 4) {
      int r = l8[ri];
      int cand = pi1[cslot * N_ROWS + r];
      const float* xp = X + (size_t)r * DIM + part * 32;
      const float* cp = C + (size_t)cand * DIM + part * 32;
      float dot = 0.f;
#pragma unroll
      for (int k = 0; k < 32; k += 4) {
        float4 xv = *(const float4*)(xp + k);
        float4 cv = *(const float4*)(cp + k);
        dot += xv.x * cv.x + xv.y * cv.y + xv.z * cv.z + xv.w * cv.w;
      }
#pragma unroll
      for (int off = 8; off < 64; off <<= 1) dot += __shfl_xor(dot, off);
      float sxq = sumsq[r];
      float d = (sxq - 2.0f * dot) + csq[cand];   // exact ref fp32 op order
      float bv = d; int bi = cand;
#pragma unroll
      for (int off = 1; off < 8; off <<= 1) {
        float ov = __shfl_xor(bv, off);
        int oi = __shfl_xor(bi, off);
        bool take = (ov < bv) || (ov == bv && oi < bi);
        bv = take ? ov : bv; bi = take ? oi : bi;
      }
      if (lane == 0) {
        out_idx[r] = (float)bi;
        idxbuf[r] = bi;
        atomicAdd(&counts[bi], 1.0f);
      }
    }
  }
}

// tier-3 exact full-scan re-solve via CT; one row per block-iteration.
#define RGRID 512
__global__ __launch_bounds__(256) void vq_rescue(
    const float* __restrict__ X, const float* __restrict__ CT,
    const float* __restrict__ sumsq, const float* __restrict__ csq,
    const int* __restrict__ rcnt, const int* __restrict__ rlist,
    float* __restrict__ out_idx, int* __restrict__ idxbuf, float* __restrict__ counts)
{
  __shared__ __align__(16) float sx[DIM];
  __shared__ float swv[4];
  __shared__ int swi[4];
  const int tid = threadIdx.x;
  const int wv = tid >> 6, lane = tid & 63;

  const int nr = rcnt[0];
  const int c0 = tid * 8;
  for (int base = blockIdx.x; base < nr; base += RGRID) {
    __syncthreads();                       // protect prior-iter LDS reads
    int row = rlist[base];
    sx[tid] = X[(size_t)row * DIM + tid];
    __syncthreads();

    float acc[8];
#pragma unroll
    for (int j = 0; j < 8; ++j) acc[j] = 0.0f;

    for (int k = 0; k < DIM; k += 4) {
      float4 xr = *(const float4*)&sx[k];
      float cv[4][8];
#pragma unroll
      for (int i = 0; i < 4; ++i) {
        float4 a = *(const float4*)(CT + (size_t)(k + i) * KCENT + c0);
        float4 b = *(const float4*)(CT + (size_t)(k + i) * KCENT + c0 + 4);
        cv[i][0] = a.x; cv[i][1] = a.y; cv[i][2] = a.z; cv[i][3] = a.w;
        cv[i][4] = b.x; cv[i][5] = b.y; cv[i][6] = b.z; cv[i][7] = b.w;
      }
#pragma unroll
      for (int j = 0; j < 8; ++j)
        acc[j] += xr.x * cv[0][j] + xr.y * cv[1][j]
                + xr.z * cv[2][j] + xr.w * cv[3][j];
    }

    float sxq = sumsq[row];
    float bv = 3.4e38f;
    int bi = 0;
#pragma unroll
    for (int j = 0; j < 8; ++j) {
      int c = c0 + j;
      float d = (sxq - 2.0f * acc[j]) + csq[c];  // exact ref fp32 op order
      if (d < bv) { bv = d; bi = c; }            // ascending c: lowest-idx tie
    }
#pragma unroll
    for (int off = 1; off < 64; off <<= 1) {
      float ov = __shfl_xor(bv, off);
      int oi = __shfl_xor(bi, off);
      bool take = (ov < bv) || (ov == bv && oi < bi);
      bv = take ? ov : bv;
      bi = take ? oi : bi;
    }
    if (lane == 0) { swv[wv] = bv; swi[wv] = bi; }
    __syncthreads();
    if (tid == 0) {
      float fv = swv[0]; int fi = swi[0];
#pragma unroll
      for (int w = 1; w < 4; ++w) {
        float ov = swv[w]; int oi = swi[w];
        if (ov < fv || (ov == fv && oi < fi)) { fv = ov; fi = oi; }
      }
      out_idx[row] = (float)fi;
      idxbuf[row] = fi;
      atomicAdd(&counts[fi], 1.0f);
    }
  }
}

// ============================================================================
//                     fp32 FALLBACK PATH (round-1 kernels)
// ============================================================================

__global__ __launch_bounds__(256) void vq_precompute(
    const float* __restrict__ X, const float* __restrict__ C,
    float* __restrict__ sumsq, float* __restrict__ csq, float* __restrict__ counts)
{
  int bid = blockIdx.x, tid = threadIdx.x;
  int wave = tid >> 6, lane = tid & 63;
  if (bid < 8192) {
    int row = bid * 4 + wave;
    float4 v = *(const float4*)(X + (size_t)row * DIM + lane * 4);
    float s = v.x * v.x + v.y * v.y + v.z * v.z + v.w * v.w;
#pragma unroll
    for (int off = 32; off > 0; off >>= 1) s += __shfl_down(s, off);
    if (lane == 0) sumsq[row] = s;
  } else if (bid < 8704) {
    int cent = (bid - 8192) * 4 + wave;
    float4 v = *(const float4*)(C + (size_t)cent * DIM + lane * 4);
    float s = v.x * v.x + v.y * v.y + v.z * v.z + v.w * v.w;
#pragma unroll
    for (int off = 32; off > 0; off >>= 1) s += __shfl_down(s, off);
    if (lane == 0) csq[cent] = s;
  } else {
    for (int i = tid; i < KCENT; i += 256) counts[i] = 0.0f;
  }
}

__global__ __launch_bounds__(256) void vq_argmin(
    const float* __restrict__ X, const float* __restrict__ C,
    const float* __restrict__ sumsq, const float* __restrict__ csq,
    float* __restrict__ pval, int* __restrict__ pidx)
{
  __shared__ __align__(16) float sA[BM * LSTR];
  __shared__ __align__(16) float sB[BN * LSTR];

  const int tid = threadIdx.x;
  const int tx = tid & 15, ty = tid >> 4;
  const int row0 = blockIdx.x * BM;
  const int g = blockIdx.y;
  const int cg0 = g * CPG;

  float sx[4];
#pragma unroll
  for (int m = 0; m < 4; ++m) sx[m] = sumsq[row0 + ty + 16 * m];

  float rmin[4];
  int ridx[4];
#pragma unroll
  for (int m = 0; m < 4; ++m) { rmin[m] = 3.4e38f; ridx[m] = 0; }

  for (int t = 0; t < CPG / BN; ++t) {
    const int c0 = cg0 + t * BN;
    float acc[4][4];
#pragma unroll
    for (int m = 0; m < 4; ++m)
#pragma unroll
      for (int n = 0; n < 4; ++n) acc[m][n] = 0.0f;

    for (int kc = 0; kc < DIM; kc += BKK) {
      __syncthreads();
#pragma unroll
      for (int s = 0; s < 2; ++s) {
        int id = tid + s * 256;
        int rr = id >> 3;
        int c4 = (id & 7) << 2;
        float4 va = *(const float4*)(X + (size_t)(row0 + rr) * DIM + kc + c4);
        *(float4*)&sA[rr * LSTR + c4] = va;
        float4 vb = *(const float4*)(C + (size_t)(c0 + rr) * DIM + kc + c4);
        *(float4*)&sB[rr * LSTR + c4] = vb;
      }
      __syncthreads();
#pragma unroll
      for (int j = 0; j < BKK; j += 4) {
        float4 a[4], b[4];
#pragma unroll
        for (int m = 0; m < 4; ++m) a[m] = *(const float4*)&sA[(ty + 16 * m) * LSTR + j];
#pragma unroll
        for (int n = 0; n < 4; ++n) b[n] = *(const float4*)&sB[(tx + 16 * n) * LSTR + j];
#pragma unroll
        for (int m = 0; m < 4; ++m)
#pragma unroll
          for (int n = 0; n < 4; ++n)
            acc[m][n] += a[m].x * b[n].x + a[m].y * b[n].y + a[m].z * b[n].z + a[m].w * b[n].w;
      }
    }

#pragma unroll
    for (int m = 0; m < 4; ++m) {
#pragma unroll
      for (int n = 0; n < 4; ++n) {
        int cent = c0 + tx + 16 * n;
        float d = (sx[m] - 2.0f * acc[m][n]) + csq[cent];
        if (d < rmin[m]) { rmin[m] = d; ridx[m] = cent; }
      }
    }
  }

  __syncthreads();
  float* rv = sA;
  int* ri = (int*)sB;
#pragma unroll
  for (int m = 0; m < 4; ++m) {
    rv[(ty + 16 * m) * 16 + tx] = rmin[m];
    ri[(ty + 16 * m) * 16 + tx] = ridx[m];
  }
  __syncthreads();
  if (tid < 64) {
    float bvv = rv[tid * 16];
    int bii = ri[tid * 16];
#pragma unroll
    for (int t2 = 1; t2 < 16; ++t2) {
      float v = rv[tid * 16 + t2];
      int i = ri[tid * 16 + t2];
      if (v < bvv || (v == bvv && i < bii)) { bvv = v; bii = i; }
    }
    pval[g * N_ROWS + row0 + tid] = bvv;
    pidx[g * N_ROWS + row0 + tid] = bii;
  }
}

__global__ __launch_bounds__(256) void vq_reduce(
    const float* __restrict__ pval, const int* __restrict__ pidx,
    float* __restrict__ out_idx, int* __restrict__ idxbuf, float* __restrict__ counts)
{
  int r = blockIdx.x * 256 + threadIdx.x;
  float bv = pval[r];
  int bi = pidx[r];
#pragma unroll
  for (int gg = 1; gg < NSPLIT; ++gg) {
    float v = pval[gg * N_ROWS + r];
    int i = pidx[gg * N_ROWS + r];
    if (v < bv || (v == bv && i < bi)) { bv = v; bi = i; }
  }
  out_idx[r] = (float)bi;
  idxbuf[r] = bi;
  atomicAdd(&counts[bi], 1.0f);
}

// ---------------- shared outputs kernel -------------------------------------
__global__ __launch_bounds__(256) void vq_outputs(
    const float* __restrict__ X, const float* __restrict__ C,
    const float* __restrict__ cc, const int* __restrict__ idxbuf,
    const float* __restrict__ counts, float* __restrict__ out)
{
  int bid = blockIdx.x, tid = threadIdx.x;
  if (bid < 8192) {
    int f4 = bid * 256 + tid;
    int row = f4 >> 6;
    int col = (f4 & 63) << 2;
    int idx = idxbuf[row];
    float4 x = *(const float4*)(X + (size_t)row * DIM + col);
    float4 q = *(const float4*)(C + (size_t)idx * DIM + col);
    float4 o, l;
    float dx = q.x - x.x, dy = q.y - x.y, dz = q.z - x.z, dw = q.w - x.w;
    o.x = x.x + dx; o.y = x.y + dy; o.z = x.z + dz; o.w = x.w + dw;
    float s0 = dx * dx, s1 = dy * dy, s2 = dz * dz, s3 = dw * dw;
    l.x = s0 + 0.25f * s0; l.y = s1 + 0.25f * s1;
    l.z = s2 + 0.25f * s2; l.w = s3 + 0.25f * s3;
    *(float4*)(out + OUT_Q + (size_t)f4 * 4) = o;
    *(float4*)(out + OUT_LOSS + (size_t)f4 * 4) = l;
  } else if (bid < 8704) {
    int f4 = (bid - 8192) * 256 + tid;
    float4 v = *(const float4*)(C + (size_t)f4 * 4);
    *(float4*)(out + OUT_CB + (size_t)f4 * 4) = v;
  } else {
    for (int i = tid; i < KCENT; i += 256)
      out[OUT_CNT + i] = 0.99f * cc[i] + 0.01f * counts[i];
  }
}

// ============================================================================
extern "C" void kernel_launch(void* const* d_in, const int* in_sizes, int n_in,
                              void* d_out, int out_size, void* d_ws, size_t ws_size,
                              hipStream_t stream) {
  const float* X = (const float*)d_in[0];
  const float* C = (const float*)d_in[1];
  const float* cc = (const float*)d_in[2];
  float* out = (float*)d_out;
  char* wsb = (char*)d_ws;

  if (ws_size >= WS_NEED) {
    // ---------------- MFMA path (4 launches) ----------------
    _Float16* A2 = (_Float16*)(wsb + WB_A2);
    _Float16* B2 = (_Float16*)(wsb + WB_B2);
    float* pv1 = (float*)(wsb + WB_PV1);
    int* pi1 = (int*)(wsb + WB_PI1);
    float* pv2 = (float*)(wsb + WB_PV2);
    float* sumsq = (float*)(wsb + WB_SUMSQ);
    float* xlo_n = (float*)(wsb + WB_XLO);
    float* xr_n = (float*)(wsb + WB_XR);
    float* csq = (float*)(wsb + WB_CSQ);
    float* counts = (float*)(wsb + WB_COUNTS);
    int* idxbuf = (int*)(wsb + WB_IDXBUF);
    int* rlist = (int*)(wsb + WB_RLIST);
    int* rcnt = (int*)(wsb + WB_MISC);
    float* CT = (float*)(wsb + WB_CT);
    float* pbmax = (float*)(wsb + WB_PBMAX);
    int* tilecnt = (int*)(wsb + WB_TILEC);

    vq_conv<<<8736, 256, 0, stream>>>(X, C, A2, B2, sumsq, xlo_n, xr_n,
                                      csq, pbmax, CT, counts, rcnt, tilecnt);
    vq_mfma<<<dim3(4, N_ROWS / GBM), 256, 0, stream>>>(
        A2, B2, csq, pv1, pi1, pv2, X, C, sumsq, xlo_n, xr_n, pbmax,
        out + OUT_IDX, idxbuf, counts, rcnt, rlist, tilecnt);
    vq_rescue<<<RGRID, 256, 0, stream>>>(X, CT, sumsq, csq, rcnt, rlist,
                                         out + OUT_IDX, idxbuf, counts);
    vq_outputs<<<8705, 256, 0, stream>>>(X, C, cc, idxbuf, counts, out);
  } else {
    // ---------------- fp32 fallback (round-1) ----------------
    float* ws = (float*)d_ws;
    float* sumsq = ws + WS_SUMSQ;
    float* csq = ws + WS_CSQ;
    float* counts = ws + WS_COUNTS;
    int* idxbuf = (int*)(ws + WS_IDX);
    float* pval = ws + WS_PVAL;
    int* pidx = (int*)(ws + WS_PIDX);

    vq_precompute<<<8705, 256, 0, stream>>>(X, C, sumsq, csq, counts);
    vq_argmin<<<dim3(N_ROWS / BM, NSPLIT), 256, 0, stream>>>(X, C, sumsq, csq, pval, pidx);
    vq_reduce<<<N_ROWS / 256, 256, 0, stream>>>(pval, pidx, out + OUT_IDX, idxbuf, counts);
    vq_outputs<<<8705, 256, 0, stream>>>(X, C, cc, idxbuf, counts, out);
  }
}

// Round 13
// 205.306 us; speedup vs baseline: 1.3406x; 1.3406x over previous
//
#include <hip/hip_runtime.h>
#include <math.h>

typedef unsigned short ushort_t;

#define N_ROWS 32768
#define DIM 256
#define KCENT 2048

// ---------------- fp32 fallback path constants (round-1 kernel) -------------
#define NSPLIT 4
#define CPG (KCENT / NSPLIT)
#define BM 64
#define BN 64
#define BKK 32
#define LSTR 36

#define WS_SUMSQ  0
#define WS_CSQ    32768
#define WS_COUNTS 34816
#define WS_IDX    36864
#define WS_PVAL   69632
#define WS_PIDX   200704

// ---------------- output layout (float offsets) -----------------------------
#define OUT_Q    0
#define OUT_LOSS 8388608
#define OUT_IDX  16777216
#define OUT_CB   16809984
#define OUT_CNT  17334272

// ---------------- MFMA path workspace (byte offsets) ------------------------
// hi-only f16 operands (K=256). 8 partial groups per row (4 g x 2 wn-halves).
#define WB_A2     0UL            // 32768 x 256 f16 = x_hi   (16 MB)
#define WB_B2     16777216UL     // 2048 x 256 f16 = c_hi    (1 MB)
#define WB_PV1    17825792UL     // 8 x 32768 f32  (1 MB)
#define WB_PI1    18874368UL     // 8 x 32768 i32  (1 MB)
#define WB_PV2    19922944UL     // 8 x 32768 f32  (1 MB)
#define WB_SUMSQ  20971520UL     // 32768 f32 (exact ||x||^2)
#define WB_XLO    21102592UL     // 32768 f32 (||x_lo||)
#define WB_XR     21233664UL     // 32768 f32 (||r_x||)
#define WB_CSQ    21364736UL     // 2048 f32 (exact ||c||^2)
#define WB_COUNTS 21372928UL     // 2048 f32
#define WB_IDXBUF 21381120UL     // 32768 i32
#define WB_RLIST  21512192UL     // 32768 i32
#define WB_MISC   21643264UL     // rcnt(i32) @ +0, rcnt8(i32) @ +4
#define WB_CT     21643328UL     // 256 x 2048 f32 transposed codebook (2 MB)
#define WB_PBMAX  23740480UL     // 512 x 3 f32 per-block partial maxes
#define WB_RLIST8 23746624UL     // 32768 i32 (8-cand-certified rows)
#define WS_NEED   23877696UL

// ---------------- types & helpers -------------------------------------------
typedef _Float16 half4 __attribute__((ext_vector_type(4)));
typedef _Float16 half8 __attribute__((ext_vector_type(8)));
typedef float f32x4 __attribute__((ext_vector_type(4)));

#define ASYNC_COPY16(gptr, lptr)                                               \
  __builtin_amdgcn_global_load_lds(                                            \
      (const __attribute__((address_space(1))) void*)(gptr),                   \
      (__attribute__((address_space(3))) void*)(lptr), 16, 0, 0)

// ============================================================================
//                               MFMA PATH (f16 hi-only + certified window)
// ============================================================================

// fused front-end, 8736 blocks (ONE launch):
//  bid <  8192      : X rows -> f16 hi + norms
//  8192 <= bid<8704 : C cents -> f16 hi + csq + per-block partial maxes
//  8704 <= bid<8736 : transpose C tile -> CT; bid==8704 zeroes counts/rcnt
// (all three ranges independent: read only kernel inputs X/C)
__global__ __launch_bounds__(256) void vq_conv(
    const float* __restrict__ X, const float* __restrict__ C,
    _Float16* __restrict__ A2, _Float16* __restrict__ B2,
    float* __restrict__ sumsq, float* __restrict__ xlo_n, float* __restrict__ xr_n,
    float* __restrict__ csq, float* __restrict__ pbmax,
    float* __restrict__ CT, float* __restrict__ counts, int* __restrict__ rcnt)
{
  __shared__ float sm[4][3];
  __shared__ float t[64][65];
  const int bid = blockIdx.x;
  const int tid = threadIdx.x;
  const int wave = tid >> 6;
  const int lane = tid & 63;

  if (bid < 8192) {
    int row = bid * 4 + wave;
    float4 v = *(const float4*)(X + (size_t)row * DIM + lane * 4);
    float xv[4] = {v.x, v.y, v.z, v.w};
    half4 hv;
    float s2 = 0.f, l2 = 0.f, r2 = 0.f;
#pragma unroll
    for (int e = 0; e < 4; ++e) {
      float x = xv[e];
      _Float16 h = (_Float16)x;          // RNE
      float hf = (float)h;
      float lrem = x - hf;
      _Float16 l = (_Float16)lrem;
      float lf = (float)l;
      float r = lrem - lf;
      hv[e] = h;
      s2 += x * x; l2 += lf * lf; r2 += r * r;
    }
    *(half4*)(A2 + (size_t)row * 256 + lane * 4) = hv;
#pragma unroll
    for (int off = 32; off > 0; off >>= 1) {
      s2 += __shfl_down(s2, off);
      l2 += __shfl_down(l2, off);
      r2 += __shfl_down(r2, off);
    }
    if (lane == 0) { sumsq[row] = s2; xlo_n[row] = sqrtf(l2); xr_n[row] = sqrtf(r2); }
  } else if (bid < 8704) {
    int cb = bid - 8192;
    int c = cb * 4 + wave;
    float4 v = *(const float4*)(C + (size_t)c * DIM + lane * 4);
    float xv[4] = {v.x, v.y, v.z, v.w};
    half4 hv;
    float s2 = 0.f, l2 = 0.f, r2 = 0.f;
#pragma unroll
    for (int e = 0; e < 4; ++e) {
      float x = xv[e];
      _Float16 h = (_Float16)x;
      float hf = (float)h;
      float lrem = x - hf;
      _Float16 l = (_Float16)lrem;
      float lf = (float)l;
      float r = lrem - lf;
      hv[e] = h;
      s2 += x * x; l2 += lf * lf; r2 += r * r;
    }
    *(half4*)(B2 + (size_t)c * 256 + lane * 4) = hv;
#pragma unroll
    for (int off = 32; off > 0; off >>= 1) {
      s2 += __shfl_down(s2, off);
      l2 += __shfl_down(l2, off);
      r2 += __shfl_down(r2, off);
    }
    if (lane == 0) {
      csq[c] = s2;
      sm[wave][0] = sqrtf(l2);   // ||c_lo||
      sm[wave][1] = sqrtf(s2);   // ||c||
      sm[wave][2] = sqrtf(r2);   // ||r_c||
    }
    __syncthreads();
    if (tid == 0) {
      float m0 = sm[0][0], m1 = sm[0][1], m2 = sm[0][2];
#pragma unroll
      for (int w = 1; w < 4; ++w) {
        m0 = fmaxf(m0, sm[w][0]);
        m1 = fmaxf(m1, sm[w][1]);
        m2 = fmaxf(m2, sm[w][2]);
      }
      pbmax[cb * 3 + 0] = m0;
      pbmax[cb * 3 + 1] = m1;
      pbmax[cb * 3 + 2] = m2;
    }
  } else {
    // transpose tile: cents [c0, c0+64)
    const int c0 = (bid - 8704) * 64;
    if (bid == 8704) {
      for (int i = tid; i < KCENT; i += 256) counts[i] = 0.0f;
      if (tid == 0) { rcnt[0] = 0; rcnt[1] = 0; }
    }
    for (int dt = 0; dt < 4; ++dt) {
      const int d0 = dt * 64;
      __syncthreads();                 // protect prior-iter LDS reads
#pragma unroll
      for (int p = 0; p < 4; ++p) {
        int id = tid + p * 256;        // 0..1023
        int r = id >> 4;               // cent-in-tile 0..63
        int c4 = (id & 15) * 4;        // dim-in-tile 0..60
        float4 v = *(const float4*)(C + (size_t)(c0 + r) * DIM + d0 + c4);
        t[r][c4 + 0] = v.x; t[r][c4 + 1] = v.y;
        t[r][c4 + 2] = v.z; t[r][c4 + 3] = v.w;
      }
      __syncthreads();
#pragma unroll
      for (int p = 0; p < 4; ++p) {
        int id = tid + p * 256;
        int d = id >> 4;               // dim-in-tile
        int cg = (id & 15) * 4;        // cent-in-tile group
        float4 w;
        w.x = t[cg + 0][d]; w.y = t[cg + 1][d];
        w.z = t[cg + 2][d]; w.w = t[cg + 3][d];
        *(float4*)(CT + (size_t)(d0 + d) * KCENT + c0 + cg) = w;
      }
    }
  }
}

// MFMA GEMM (hi*hi only, K=256) + fused argmin(+2nd-min).
// ROUND-11 VERIFIED STRUCTURE (56 us, VGPR 120, occ ~19.5%): BK=64 (32
// barriers), acc[4][4], conflict-free both-sides XOR swizzle, XCD remap.
// DO NOT add code to this kernel: round-12's last-block tail fusion pushed
// VGPR 120->132 (over the 128 cliff), occ 19.7->11%, dur 56->136 us. Same
// failure as round-7's med3 (116->148). The GEMM stays single-purpose.
// Epilogue MUST stay fminf/fmaxf form.
#define GBM 128
#define GBN 128
#define GBK 64
__global__ __launch_bounds__(256) void vq_mfma(
    const _Float16* __restrict__ A2, const _Float16* __restrict__ B2,
    const float* __restrict__ csq,
    float* __restrict__ pv1, int* __restrict__ pi1, float* __restrict__ pv2)
{
  __shared__ __align__(16) _Float16 sA[GBM * GBK];   // 16 KB
  __shared__ __align__(16) _Float16 sB[GBN * GBK];   // 16 KB

  const int tid = threadIdx.x;
  const int wave = tid >> 6, lane = tid & 63;
  const int lc = lane & 15, quad = lane >> 4;
  const int wm = wave >> 1, wn = wave & 1;

  // bijective XCD-aware remap: lin = g + 4*y; xcd gets 32 consecutive y x 4 g
  const int lin = blockIdx.x + 4 * blockIdx.y;
  const int xcd = lin & 7;
  const int per = lin >> 3;            // 0..127
  const int yb = xcd * 32 + (per & 31);
  const int g = per >> 5;              // 0..3
  const int row0 = yb * GBM;

  const int rsw = lc & 7;                                   // read-side row swizzle key
  const int sko = (((lane & 7) ^ ((lane >> 3) & 7)) << 3);  // source-side (elems)

  float m1[4][4], m2[4][4];
  int i1v[4][4];
#pragma unroll
  for (int i = 0; i < 4; ++i)
#pragma unroll
    for (int r = 0; r < 4; ++r) { m1[i][r] = 3.4e38f; m2[i][r] = 3.4e38f; i1v[i][r] = 0; }

  const int st_row = lane >> 3;        // 8 rows per wave-call
  const _Float16* gA = A2 + (size_t)(row0 + wave * 32 + st_row) * 256 + sko;

  for (int ct = 0; ct < 4; ++ct) {
    const int cb0 = g * 512 + ct * 128;
    const _Float16* gB = B2 + (size_t)(cb0 + wave * 32 + st_row) * 256 + sko;
    float cs[4];
#pragma unroll
    for (int j = 0; j < 4; ++j) cs[j] = csq[cb0 + wn * 64 + j * 16 + lc];

    f32x4 acc[4][4] = {};

    for (int kt = 0; kt < 4; ++kt) {
      const int k0 = kt * 64;
      __syncthreads();
#pragma unroll
      for (int j = 0; j < 4; ++j) {
        ASYNC_COPY16(gA + (size_t)(j * 8) * 256 + k0, &sA[(wave * 32 + j * 8) * GBK]);
        ASYNC_COPY16(gB + (size_t)(j * 8) * 256 + k0, &sB[(wave * 32 + j * 8) * GBK]);
      }
      __syncthreads();
#pragma unroll
      for (int h = 0; h < 2; ++h) {
        half8 fa[4], fb[4];
#pragma unroll
        for (int i = 0; i < 4; ++i)
          fa[i] = *(const half8*)&sA[(wm * 64 + i * 16 + lc) * GBK
                                     + (((h << 2) + quad) ^ rsw) * 8];
#pragma unroll
        for (int j = 0; j < 4; ++j)
          fb[j] = *(const half8*)&sB[(wn * 64 + j * 16 + lc) * GBK
                                     + (((h << 2) + quad) ^ rsw) * 8];
#pragma unroll
        for (int i = 0; i < 4; ++i)
#pragma unroll
          for (int j = 0; j < 4; ++j)
            acc[i][j] = __builtin_amdgcn_mfma_f32_16x16x32_f16(fa[i], fb[j], acc[i][j], 0, 0, 0);
      }
    }

#pragma unroll
    for (int i = 0; i < 4; ++i) {
#pragma unroll
      for (int j = 0; j < 4; ++j) {
        const int cent = cb0 + wn * 64 + j * 16 + lc;
#pragma unroll
        for (int r = 0; r < 4; ++r) {
          float d = fmaf(-2.0f, acc[i][j][r], cs[j]);
          bool cnd = d < m1[i][r];
          i1v[i][r] = cnd ? cent : i1v[i][r];
          m2[i][r] = fminf(m2[i][r], fmaxf(d, m1[i][r]));
          m1[i][r] = fminf(d, m1[i][r]);
        }
      }
    }
  }

#pragma unroll
  for (int i = 0; i < 4; ++i) {
#pragma unroll
    for (int r = 0; r < 4; ++r) {
      float a1 = m1[i][r], a2 = m2[i][r];
      int ai = i1v[i][r];
#pragma unroll
      for (int off = 1; off < 16; off <<= 1) {
        float o1 = __shfl_xor(a1, off);
        int oi = __shfl_xor(ai, off);
        float o2 = __shfl_xor(a2, off);
        float big = fmaxf(a1, o1);
        bool cnd = o1 < a1;
        a1 = fminf(a1, o1);
        ai = cnd ? oi : ai;
        a2 = fminf(fminf(a2, o2), big);
      }
      if (lc == 0) {
        const int row = row0 + wm * 64 + i * 16 + quad * 4 + r;
        const int slot = g * 2 + wn;
        pv1[slot * N_ROWS + row] = a1;
        pi1[slot * N_ROWS + row] = ai;
        pv2[slot * N_ROWS + row] = a2;
      }
    }
  }
}

// merge 8 partial groups/row; three-way certify (maxes computed per-block
// from pbmax -- same fmax tree values, launch for vq_maxred eliminated):
//  (1) m2-m1 >= W -> top-1 certified (count it)
//  (2) q-m1 >= W  -> argmin provably in {pi1[s]}_8 (q = min_s pv2[s])
//  (3) else       -> full exact rescue.
__global__ __launch_bounds__(256) void vq_flagreduce(
    const float* __restrict__ pv1, const int* __restrict__ pi1,
    const float* __restrict__ pv2,
    const float* __restrict__ sumsq, const float* __restrict__ xlo_n,
    const float* __restrict__ xr_n, const float* __restrict__ pbmax,
    float* __restrict__ out_idx, int* __restrict__ idxbuf,
    float* __restrict__ counts, int* __restrict__ rcnt,
    int* __restrict__ rlist, int* __restrict__ rlist8)
{
  __shared__ float smx[4][3];
  __shared__ float bmx[3];
  const int tid = threadIdx.x;
  const int wave = tid >> 6, lane = tid & 63;

  // per-block reduce of pbmax[512][3] (L2-hit, ~1536 loads)
  float a0 = 0.f, a1b = 0.f, a2b = 0.f;
  for (int i = tid; i < KCENT / 4; i += 256) {
    a0 = fmaxf(a0, pbmax[i * 3 + 0]);
    a1b = fmaxf(a1b, pbmax[i * 3 + 1]);
    a2b = fmaxf(a2b, pbmax[i * 3 + 2]);
  }
#pragma unroll
  for (int off = 32; off > 0; off >>= 1) {
    a0 = fmaxf(a0, __shfl_down(a0, off));
    a1b = fmaxf(a1b, __shfl_down(a1b, off));
    a2b = fmaxf(a2b, __shfl_down(a2b, off));
  }
  if (lane == 0) { smx[wave][0] = a0; smx[wave][1] = a1b; smx[wave][2] = a2b; }
  __syncthreads();
  if (tid == 0) {
#pragma unroll
    for (int w = 1; w < 4; ++w) {
      a0 = fmaxf(a0, smx[w][0]);
      a1b = fmaxf(a1b, smx[w][1]);
      a2b = fmaxf(a2b, smx[w][2]);
    }
    bmx[0] = a0; bmx[1] = a1b; bmx[2] = a2b;
  }
  __syncthreads();
  const float maxL = bmx[0];   // max ||c_lo||
  const float maxC = bmx[1];   // max ||c||
  const float maxR = bmx[2];   // max ||r_c||

  int r = blockIdx.x * 256 + tid;
  float m1 = pv1[r]; int i1 = pi1[r]; float m2 = pv2[r];
  float q = pv2[r];
#pragma unroll
  for (int gg = 1; gg < 8; ++gg) {
    float o1 = pv1[gg * N_ROWS + r];
    int oi = pi1[gg * N_ROWS + r];
    float o2 = pv2[gg * N_ROWS + r];
    q = fminf(q, o2);
    float big = fmaxf(m1, o1);
    bool cnd = o1 < m1;
    m1 = fminf(m1, o1);
    i1 = cnd ? oi : i1;
    m2 = fminf(fminf(m2, o2), big);
  }
  float xl = xlo_n[r];
  float xr = xr_n[r];
  float xn = sqrtf(sumsq[r]);
  float errdot = (xl + xr) * maxC + (xn + xl + xr) * (maxL + maxR);
  float W = 2.0f * errdot + 1e-3f;          // certified bound + fp32 slack
  out_idx[r] = (float)i1;
  idxbuf[r] = i1;
  if (m2 - m1 >= W) {
    atomicAdd(&counts[i1], 1.0f);
  } else if (q - m1 >= W) {
    int p = atomicAdd(rcnt + 1, 1);
    rlist8[p] = r;
  } else {
    int p = atomicAdd(rcnt, 1);
    rlist[p] = r;
  }
}

// fused rescue (ONE launch): phase 1 = exact 8-candidate re-solve (wave/row);
// phase 2 = exact full-scan re-solve via CT (block/row). Phases independent.
#define RGRID 512
__global__ __launch_bounds__(256) void vq_rescue_both(
    const float* __restrict__ X, const float* __restrict__ C,
    const float* __restrict__ CT,
    const float* __restrict__ sumsq, const float* __restrict__ csq,
    const int* __restrict__ rcnt, const int* __restrict__ rlist,
    const int* __restrict__ rlist8, const int* __restrict__ pi1,
    float* __restrict__ out_idx, int* __restrict__ idxbuf, float* __restrict__ counts)
{
  __shared__ __align__(16) float sx[DIM];
  __shared__ float swv[4];
  __shared__ int swi[4];
  const int tid = threadIdx.x;
  const int wv = tid >> 6, lane = tid & 63;

  // ---- phase 1: 8-candidate rows (no LDS use) ----
  const int nr8 = rcnt[1];
  const int cslot = lane & 7;
  const int part = lane >> 3;
  for (int ri = blockIdx.x * 4 + wv; ri < nr8; ri += RGRID * 4) {
    int r = rlist8[ri];
    int cand = pi1[cslot * N_ROWS + r];
    const float* xp = X + (size_t)r * DIM + part * 32;
    const float* cp = C + (size_t)cand * DIM + part * 32;
    float dot = 0.f;
#pragma unroll
    for (int k = 0; k < 32; k += 4) {
      float4 xv = *(const float4*)(xp + k);
      float4 cv = *(const float4*)(cp + k);
      dot += xv.x * cv.x + xv.y * cv.y + xv.z * cv.z + xv.w * cv.w;
    }
#pragma unroll
    for (int off = 8; off < 64; off <<= 1) dot += __shfl_xor(dot, off);
    float sxq = sumsq[r];
    float d = (sxq - 2.0f * dot) + csq[cand];   // exact ref fp32 op order
    float bv = d; int bi = cand;
#pragma unroll
    for (int off = 1; off < 8; off <<= 1) {
      float ov = __shfl_xor(bv, off);
      int oi = __shfl_xor(bi, off);
      bool take = (ov < bv) || (ov == bv && oi < bi);
      bv = take ? ov : bv; bi = take ? oi : bi;
    }
    if (lane == 0) {
      out_idx[r] = (float)bi;
      idxbuf[r] = bi;
      atomicAdd(&counts[bi], 1.0f);
    }
  }

  // ---- phase 2: full-scan rows, one row per block-iteration ----
  const int nr = rcnt[0];
  const int c0 = tid * 8;
  for (int base = blockIdx.x; base < nr; base += RGRID) {
    __syncthreads();                       // protect prior-iter LDS reads
    int row = rlist[base];
    sx[tid] = X[(size_t)row * DIM + tid];
    __syncthreads();

    float acc[8];
#pragma unroll
    for (int j = 0; j < 8; ++j) acc[j] = 0.0f;

    for (int k = 0; k < DIM; k += 4) {
      float4 xr = *(const float4*)&sx[k];
      float cv[4][8];
#pragma unroll
      for (int i = 0; i < 4; ++i) {
        float4 a = *(const float4*)(CT + (size_t)(k + i) * KCENT + c0);
        float4 b = *(const float4*)(CT + (size_t)(k + i) * KCENT + c0 + 4);
        cv[i][0] = a.x; cv[i][1] = a.y; cv[i][2] = a.z; cv[i][3] = a.w;
        cv[i][4] = b.x; cv[i][5] = b.y; cv[i][6] = b.z; cv[i][7] = b.w;
      }
#pragma unroll
      for (int j = 0; j < 8; ++j)
        acc[j] += xr.x * cv[0][j] + xr.y * cv[1][j]
                + xr.z * cv[2][j] + xr.w * cv[3][j];
    }

    float sxq = sumsq[row];
    float bv = 3.4e38f;
    int bi = 0;
#pragma unroll
    for (int j = 0; j < 8; ++j) {
      int c = c0 + j;
      float d = (sxq - 2.0f * acc[j]) + csq[c];  // exact ref fp32 op order
      if (d < bv) { bv = d; bi = c; }            // ascending c: lowest-idx tie
    }
#pragma unroll
    for (int off = 1; off < 64; off <<= 1) {
      float ov = __shfl_xor(bv, off);
      int oi = __shfl_xor(bi, off);
      bool take = (ov < bv) || (ov == bv && oi < bi);
      bv = take ? ov : bv;
      bi = take ? oi : bi;
    }
    if (lane == 0) { swv[wv] = bv; swi[wv] = bi; }
    __syncthreads();
    if (tid == 0) {
      float fv = swv[0]; int fi = swi[0];
#pragma unroll
      for (int w = 1; w < 4; ++w) {
        float ov = swv[w]; int oi = swi[w];
        if (ov < fv || (ov == fv && oi < fi)) { fv = ov; fi = oi; }
      }
      out_idx[row] = (float)fi;
      idxbuf[row] = fi;
      atomicAdd(&counts[fi], 1.0f);
    }
  }
}

// ============================================================================
//                     fp32 FALLBACK PATH (round-1 kernels)
// ============================================================================

__global__ __launch_bounds__(256) void vq_precompute(
    const float* __restrict__ X, const float* __restrict__ C,
    float* __restrict__ sumsq, float* __restrict__ csq, float* __restrict__ counts)
{
  int bid = blockIdx.x, tid = threadIdx.x;
  int wave = tid >> 6, lane = tid & 63;
  if (bid < 8192) {
    int row = bid * 4 + wave;
    float4 v = *(const float4*)(X + (size_t)row * DIM + lane * 4);
    float s = v.x * v.x + v.y * v.y + v.z * v.z + v.w * v.w;
#pragma unroll
    for (int off = 32; off > 0; off >>= 1) s += __shfl_down(s, off);
    if (lane == 0) sumsq[row] = s;
  } else if (bid < 8704) {
    int cent = (bid - 8192) * 4 + wave;
    float4 v = *(const float4*)(C + (size_t)cent * DIM + lane * 4);
    float s = v.x * v.x + v.y * v.y + v.z * v.z + v.w * v.w;
#pragma unroll
    for (int off = 32; off > 0; off >>= 1) s += __shfl_down(s, off);
    if (lane == 0) csq[cent] = s;
  } else {
    for (int i = tid; i < KCENT; i += 256) counts[i] = 0.0f;
  }
}

__global__ __launch_bounds__(256) void vq_argmin(
    const float* __restrict__ X, const float* __restrict__ C,
    const float* __restrict__ sumsq, const float* __restrict__ csq,
    float* __restrict__ pval, int* __restrict__ pidx)
{
  __shared__ __align__(16) float sA[BM * LSTR];
  __shared__ __align__(16) float sB[BN * LSTR];

  const int tid = threadIdx.x;
  const int tx = tid & 15, ty = tid >> 4;
  const int row0 = blockIdx.x * BM;
  const int g = blockIdx.y;
  const int cg0 = g * CPG;

  float sx[4];
#pragma unroll
  for (int m = 0; m < 4; ++m) sx[m] = sumsq[row0 + ty + 16 * m];

  float rmin[4];
  int ridx[4];
#pragma unroll
  for (int m = 0; m < 4; ++m) { rmin[m] = 3.4e38f; ridx[m] = 0; }

  for (int t = 0; t < CPG / BN; ++t) {
    const int c0 = cg0 + t * BN;
    float acc[4][4];
#pragma unroll
    for (int m = 0; m < 4; ++m)
#pragma unroll
      for (int n = 0; n < 4; ++n) acc[m][n] = 0.0f;

    for (int kc = 0; kc < DIM; kc += BKK) {
      __syncthreads();
#pragma unroll
      for (int s = 0; s < 2; ++s) {
        int id = tid + s * 256;
        int rr = id >> 3;
        int c4 = (id & 7) << 2;
        float4 va = *(const float4*)(X + (size_t)(row0 + rr) * DIM + kc + c4);
        *(float4*)&sA[rr * LSTR + c4] = va;
        float4 vb = *(const float4*)(C + (size_t)(c0 + rr) * DIM + kc + c4);
        *(float4*)&sB[rr * LSTR + c4] = vb;
      }
      __syncthreads();
#pragma unroll
      for (int j = 0; j < BKK; j += 4) {
        float4 a[4], b[4];
#pragma unroll
        for (int m = 0; m < 4; ++m) a[m] = *(const float4*)&sA[(ty + 16 * m) * LSTR + j];
#pragma unroll
        for (int n = 0; n < 4; ++n) b[n] = *(const float4*)&sB[(tx + 16 * n) * LSTR + j];
#pragma unroll
        for (int m = 0; m < 4; ++m)
#pragma unroll
          for (int n = 0; n < 4; ++n)
            acc[m][n] += a[m].x * b[n].x + a[m].y * b[n].y + a[m].z * b[n].z + a[m].w * b[n].w;
      }
    }

#pragma unroll
    for (int m = 0; m < 4; ++m) {
#pragma unroll
      for (int n = 0; n < 4; ++n) {
        int cent = c0 + tx + 16 * n;
        float d = (sx[m] - 2.0f * acc[m][n]) + csq[cent];
        if (d < rmin[m]) { rmin[m] = d; ridx[m] = cent; }
      }
    }
  }

  __syncthreads();
  float* rv = sA;
  int* ri = (int*)sB;
#pragma unroll
  for (int m = 0; m < 4; ++m) {
    rv[(ty + 16 * m) * 16 + tx] = rmin[m];
    ri[(ty + 16 * m) * 16 + tx] = ridx[m];
  }
  __syncthreads();
  if (tid < 64) {
    float bvv = rv[tid * 16];
    int bii = ri[tid * 16];
#pragma unroll
    for (int t2 = 1; t2 < 16; ++t2) {
      float v = rv[tid * 16 + t2];
      int i = ri[tid * 16 + t2];
      if (v < bvv || (v == bvv && i < bii)) { bvv = v; bii = i; }
    }
    pval[g * N_ROWS + row0 + tid] = bvv;
    pidx[g * N_ROWS + row0 + tid] = bii;
  }
}

__global__ __launch_bounds__(256) void vq_reduce(
    const float* __restrict__ pval, const int* __restrict__ pidx,
    float* __restrict__ out_idx, int* __restrict__ idxbuf, float* __restrict__ counts)
{
  int r = blockIdx.x * 256 + threadIdx.x;
  float bv = pval[r];
  int bi = pidx[r];
#pragma unroll
  for (int gg = 1; gg < NSPLIT; ++gg) {
    float v = pval[gg * N_ROWS + r];
    int i = pidx[gg * N_ROWS + r];
    if (v < bv || (v == bv && i < bi)) { bv = v; bi = i; }
  }
  out_idx[r] = (float)bi;
  idxbuf[r] = bi;
  atomicAdd(&counts[bi], 1.0f);
}

// ---------------- shared outputs kernel -------------------------------------
__global__ __launch_bounds__(256) void vq_outputs(
    const float* __restrict__ X, const float* __restrict__ C,
    const float* __restrict__ cc, const int* __restrict__ idxbuf,
    const float* __restrict__ counts, float* __restrict__ out)
{
  int bid = blockIdx.x, tid = threadIdx.x;
  if (bid < 8192) {
    int f4 = bid * 256 + tid;
    int row = f4 >> 6;
    int col = (f4 & 63) << 2;
    int idx = idxbuf[row];
    float4 x = *(const float4*)(X + (size_t)row * DIM + col);
    float4 q = *(const float4*)(C + (size_t)idx * DIM + col);
    float4 o, l;
    float dx = q.x - x.x, dy = q.y - x.y, dz = q.z - x.z, dw = q.w - x.w;
    o.x = x.x + dx; o.y = x.y + dy; o.z = x.z + dz; o.w = x.w + dw;
    float s0 = dx * dx, s1 = dy * dy, s2 = dz * dz, s3 = dw * dw;
    l.x = s0 + 0.25f * s0; l.y = s1 + 0.25f * s1;
    l.z = s2 + 0.25f * s2; l.w = s3 + 0.25f * s3;
    *(float4*)(out + OUT_Q + (size_t)f4 * 4) = o;
    *(float4*)(out + OUT_LOSS + (size_t)f4 * 4) = l;
  } else if (bid < 8704) {
    int f4 = (bid - 8192) * 256 + tid;
    float4 v = *(const float4*)(C + (size_t)f4 * 4);
    *(float4*)(out + OUT_CB + (size_t)f4 * 4) = v;
  } else {
    for (int i = tid; i < KCENT; i += 256)
      out[OUT_CNT + i] = 0.99f * cc[i] + 0.01f * counts[i];
  }
}

// ============================================================================
extern "C" void kernel_launch(void* const* d_in, const int* in_sizes, int n_in,
                              void* d_out, int out_size, void* d_ws, size_t ws_size,
                              hipStream_t stream) {
  const float* X = (const float*)d_in[0];
  const float* C = (const float*)d_in[1];
  const float* cc = (const float*)d_in[2];
  float* out = (float*)d_out;
  char* wsb = (char*)d_ws;

  if (ws_size >= WS_NEED) {
    // ---------------- MFMA path (5 launches) ----------------
    _Float16* A2 = (_Float16*)(wsb + WB_A2);
    _Float16* B2 = (_Float16*)(wsb + WB_B2);
    float* pv1 = (float*)(wsb + WB_PV1);
    int* pi1 = (int*)(wsb + WB_PI1);
    float* pv2 = (float*)(wsb + WB_PV2);
    float* sumsq = (float*)(wsb + WB_SUMSQ);
    float* xlo_n = (float*)(wsb + WB_XLO);
    float* xr_n = (float*)(wsb + WB_XR);
    float* csq = (float*)(wsb + WB_CSQ);
    float* counts = (float*)(wsb + WB_COUNTS);
    int* idxbuf = (int*)(wsb + WB_IDXBUF);
    int* rlist = (int*)(wsb + WB_RLIST);
    int* rcnt = (int*)(wsb + WB_MISC);
    float* CT = (float*)(wsb + WB_CT);
    float* pbmax = (float*)(wsb + WB_PBMAX);
    int* rlist8 = (int*)(wsb + WB_RLIST8);

    vq_conv<<<8736, 256, 0, stream>>>(X, C, A2, B2, sumsq, xlo_n, xr_n,
                                      csq, pbmax, CT, counts, rcnt);
    vq_mfma<<<dim3(4, N_ROWS / GBM), 256, 0, stream>>>(A2, B2, csq, pv1, pi1, pv2);
    vq_flagreduce<<<N_ROWS / 256, 256, 0, stream>>>(
        pv1, pi1, pv2, sumsq, xlo_n, xr_n, pbmax,
        out + OUT_IDX, idxbuf, counts, rcnt, rlist, rlist8);
    vq_rescue_both<<<RGRID, 256, 0, stream>>>(X, C, CT, sumsq, csq, rcnt,
                                              rlist, rlist8, pi1,
                                              out + OUT_IDX, idxbuf, counts);
    vq_outputs<<<8705, 256, 0, stream>>>(X, C, cc, idxbuf, counts, out);
  } else {
    // ---------------- fp32 fallback (round-1) ----------------
    float* ws = (float*)d_ws;
    float* sumsq = ws + WS_SUMSQ;
    float* csq = ws + WS_CSQ;
    float* counts = ws + WS_COUNTS;
    int* idxbuf = (int*)(ws + WS_IDX);
    float* pval = ws + WS_PVAL;
    int* pidx = (int*)(ws + WS_PIDX);

    vq_precompute<<<8705, 256, 0, stream>>>(X, C, sumsq, csq, counts);
    vq_argmin<<<dim3(N_ROWS / BM, NSPLIT), 256, 0, stream>>>(X, C, sumsq, csq, pval, pidx);
    vq_reduce<<<N_ROWS / 256, 256, 0, stream>>>(pval, pidx, out + OUT_IDX, idxbuf, counts);
    vq_outputs<<<8705, 256, 0, stream>>>(X, C, cc, idxbuf, counts, out);
  }
}